// Round 1
// baseline (145.375 us; speedup 1.0000x reference)
//
#include <hip/hip_runtime.h>

#define TS 1000

__device__ __forceinline__ double wred(double v) {
#pragma unroll
    for (int o = 32; o > 0; o >>= 1) v += __shfl_down(v, o, 64);
    return v;
}

__device__ __forceinline__ void scat(unsigned* bins, float v, unsigned val) {
    if (v != 0.0f) {
        int q = (int)(v * 1000.0f) - 1;
        if (q < 0) q += TS;
        atomicMax(&bins[q], val);
    }
}

__global__ void kinit(double* acc, int n) {
    int i = blockIdx.x * blockDim.x + threadIdx.x;
    if (i < n) acc[i] = 0.0;
}

// Fused kernel. Even blocks: row transform (vy) + elementwise vt, one wave per
// row, 4 rows looped per wave, per-wave 8KB bin slice. Odd blocks: column
// transform (vx), 4 columns at a time, 4 phases over a 16-column line group.
// LDS = 32000B -> 5 blocks/CU (20 waves) for both paths.
__global__ __launch_bounds__(256, 5) void kmain(const float* __restrict__ R,
                                                const float* __restrict__ T,
                                                double* __restrict__ acc,
                                                int ncopy_mask) {
    __shared__ unsigned bins[8000];
    const int tid = threadIdx.x;
    const uint4 z4 = make_uint4(0u, 0u, 0u, 0u);

    // vector clear once; readback loops re-clear as they consume
    {
        uint4* p = (uint4*)bins;
        for (int i = tid; i < 2000; i += 256) p[i] = z4;
    }
    __syncthreads();

    const int lane = tid & 63, wv = tid >> 6;
    const int id = blockIdx.x;
    double* accrow = acc + (size_t)(id & ncopy_mask) * 16;

    double s0 = 0.0, ssum = 0.0;  // bin-MSE sums (vy or vx)
    int c1 = 0;

    if ((id & 1) == 0) {
        // ================= rows: vt + vy =================
        const int kid = id >> 1;  // 0..1023, 16 rows each
        double t0 = 0.0, tsum = 0.0;
        int tc1 = 0;
        unsigned* bR = bins + wv * 2000;
        unsigned* bT = bR + 1000;
        uint4* r4 = (uint4*)bR;
        uint4* t4 = (uint4*)bT;
        for (int it = 0; it < 4; it++) {
            const size_t row = (size_t)kid * 16 + (size_t)(wv * 4 + it);
            const float4* R4 = (const float4*)(R + row * 512);
            const float4* T4 = (const float4*)(T + row * 512);
#pragma unroll
            for (int k = 0; k < 2; k++) {
                const int c = lane + k * 64;  // float4 index within row
                float4 rv = R4[c];
                float4 tv = T4[c];
                float rr[4] = {rv.x, rv.y, rv.z, rv.w};
                float tt[4] = {tv.x, tv.y, tv.z, tv.w};
#pragma unroll
                for (int j = 0; j < 4; j++) {
                    float a = rr[j], b = tt[j];
                    float d = a - b, d2 = d * d;
                    bool bz = (b == 0.0f);
                    tsum += (double)d2;
                    t0 += bz ? (double)d2 : 0.0;
                    tc1 += bz ? 0 : 1;
                    scat(bR, a, (unsigned)(c * 4 + j));
                    scat(bT, b, (unsigned)(c * 4 + j));
                }
            }
            __syncthreads();
            // readback + re-clear: 250 uint4 groups per array
            for (int g = lane; g < 250; g += 64) {
                uint4 rg = r4[g], tg = t4[g];
                r4[g] = z4;
                t4[g] = z4;
                if (rg.x | rg.y | rg.z | rg.w | tg.x | tg.y | tg.z | tg.w) {
                    unsigned ru[4] = {rg.x, rg.y, rg.z, rg.w};
                    unsigned tu[4] = {tg.x, tg.y, tg.z, tg.w};
#pragma unroll
                    for (int j = 0; j < 4; j++) {
                        float rb = (float)ru[j], tb = (float)tu[j];
                        float d = rb - tb, d2 = d * d;
                        bool tz = (tb == 0.0f);
                        ssum += (double)d2;
                        s0 += tz ? (double)d2 : 0.0;
                        c1 += tz ? 0 : 1;
                    }
                }
            }
            __syncthreads();
        }
        double v0 = wred(t0), v1 = wred(tsum), v2 = wred((double)tc1);
        double v3 = wred(s0), v4 = wred(ssum), v5 = wred((double)c1);
        if (lane == 0) {
            atomicAdd(&accrow[0], v0);
            atomicAdd(&accrow[1], v1);
            atomicAdd(&accrow[2], v2);
            atomicAdd(&accrow[3], v3);
            atomicAdd(&accrow[4], v4);
            atomicAdd(&accrow[5], v5);
        }
    } else {
        // ================= columns: vx =================
        const int kid = id >> 1;    // 0..1023
        const int b = kid >> 5;     // image
        const int line = kid & 31;  // 16-column line group
        const float* Rb = R + (size_t)b * (512 * 512) + (size_t)line * 16;
        const float* Tb = T + (size_t)b * (512 * 512) + (size_t)line * 16;
        uint4* r4 = (uint4*)bins;            // [4 cols][1000] for R
        uint4* t4 = (uint4*)(bins + 4000);   // [4 cols][1000] for T
        for (int p = 0; p < 4; p++) {
#pragma unroll
            for (int k = 0; k < 2; k++) {
                const int h = tid + k * 256;
                float4 a4 = *(const float4*)(Rb + (size_t)h * 512 + p * 4);
                float4 c4 = *(const float4*)(Tb + (size_t)h * 512 + p * 4);
                float aa[4] = {a4.x, a4.y, a4.z, a4.w};
                float cc[4] = {c4.x, c4.y, c4.z, c4.w};
#pragma unroll
                for (int j = 0; j < 4; j++) {
                    scat(bins + j * 1000, aa[j], (unsigned)h);
                    scat(bins + 4000 + j * 1000, cc[j], (unsigned)h);
                }
            }
            __syncthreads();
            // readback + re-clear: 1000 uint4 groups cover all 4 columns
            for (int g = tid; g < 1000; g += 256) {
                uint4 rg = r4[g], tg = t4[g];
                r4[g] = z4;
                t4[g] = z4;
                if (rg.x | rg.y | rg.z | rg.w | tg.x | tg.y | tg.z | tg.w) {
                    unsigned ru[4] = {rg.x, rg.y, rg.z, rg.w};
                    unsigned tu[4] = {tg.x, tg.y, tg.z, tg.w};
#pragma unroll
                    for (int j = 0; j < 4; j++) {
                        float rb = (float)ru[j], tb = (float)tu[j];
                        float d = rb - tb, d2 = d * d;
                        bool tz = (tb == 0.0f);
                        ssum += (double)d2;
                        s0 += tz ? (double)d2 : 0.0;
                        c1 += tz ? 0 : 1;
                    }
                }
            }
            __syncthreads();
        }
        double v3 = wred(s0), v4 = wred(ssum), v5 = wred((double)c1);
        if (lane == 0) {
            atomicAdd(&accrow[6], v3);
            atomicAdd(&accrow[7], v4);
            atomicAdd(&accrow[8], v5);
        }
    }
}

__global__ void kfin(const double* __restrict__ acc, float* __restrict__ out,
                     int ncopy) {
    const int lane = threadIdx.x;  // 64 threads
    double v[9];
#pragma unroll
    for (int k = 0; k < 9; k++) v[k] = 0.0;
    if (lane < ncopy) {
#pragma unroll
        for (int k = 0; k < 9; k++) v[k] = acc[(size_t)lane * 16 + k];
    }
#pragma unroll
    for (int k = 0; k < 9; k++) {
#pragma unroll
        for (int o = 16; o > 0; o >>= 1) v[k] += __shfl_down(v[k], o, 64);
    }
    if (lane == 0) {
        const double NT = 8388608.0;   // 32*512*512
        const double NB = 16384000.0;  // 32*512*1000
        double vt_c1 = v[2], vy_c1 = v[5], vx_c1 = v[8];
        double vt_c0 = NT - vt_c1, vy_c0 = NB - vy_c1, vx_c0 = NB - vx_c1;
        double vt_s1 = v[1] - v[0];
        double vy_s1 = v[4] - v[3];
        double vx_s1 = v[7] - v[6];
        double vt = (vt_c0 > 0.0 ? v[0] / vt_c0 : 0.0) +
                    (vt_c1 > 0.0 ? vt_s1 / vt_c1 : 0.0);
        double vy = (vy_c0 > 0.0 ? v[3] / vy_c0 : 0.0) +
                    (vy_c1 > 0.0 ? vy_s1 / vy_c1 : 0.0);
        double vx = (vx_c0 > 0.0 ? v[6] / vx_c0 : 0.0) +
                    (vx_c1 > 0.0 ? vx_s1 / vx_c1 : 0.0);
        out[0] = (float)(vt + vx + vy);
    }
}

extern "C" void kernel_launch(void* const* d_in, const int* in_sizes, int n_in,
                              void* d_out, int out_size, void* d_ws, size_t ws_size,
                              hipStream_t stream) {
    const float* R = (const float*)d_in[0];  // reconstructed_image
    const float* T = (const float*)d_in[1];  // target_image
    double* acc = (double*)d_ws;
    float* out = (float*)d_out;

    // power-of-two accumulator copies, line-padded (16 doubles = 128B each)
    int ncopy = 16;
    while (ncopy > 1 && (size_t)ncopy * 16 * sizeof(double) > ws_size) ncopy >>= 1;

    hipLaunchKernelGGL(kinit, dim3(1), dim3(256), 0, stream, acc, ncopy * 16);
    hipLaunchKernelGGL(kmain, dim3(2048), dim3(256), 0, stream, R, T, acc, ncopy - 1);
    hipLaunchKernelGGL(kfin, dim3(1), dim3(64), 0, stream, acc, out, ncopy);
}

// Round 2
// 77.024 us; speedup vs baseline: 1.8874x; 1.8874x over previous
//
#include <hip/hip_runtime.h>

#define TS 1000

__device__ __forceinline__ double wred(double v) {
#pragma unroll
    for (int o = 32; o > 0; o >>= 1) v += __shfl_down(v, o, 64);
    return v;
}

__device__ __forceinline__ void scat(unsigned* bins, float v, unsigned val) {
    if (v != 0.0f) {
        int q = (int)(v * 1000.0f) - 1;
        if (q < 0) q += TS;
        atomicMax(&bins[q], val);
    }
}

__global__ void kinit(double* acc, int n) {
    int i = blockIdx.x * blockDim.x + threadIdx.x;
    if (i < n) acc[i] = 0.0;
}

// Fused kernel. Even blocks: row transform (vy) + elementwise vt, one wave per
// row-quad, per-wave 8KB bin slice. Odd blocks: column transform (vx): the
// whole 512-row x 16-col stripe is loaded ONCE into registers (16 float4 per
// thread), then 4 scatter phases run from registers -> no HBM re-reads.
__global__ __launch_bounds__(256, 4) void kmain(const float* __restrict__ R,
                                                const float* __restrict__ T,
                                                double* __restrict__ acc,
                                                int ncopy_mask) {
    __shared__ unsigned bins[8000];
    const int tid = threadIdx.x;
    const uint4 z4 = make_uint4(0u, 0u, 0u, 0u);

    {
        uint4* p = (uint4*)bins;
        for (int i = tid; i < 2000; i += 256) p[i] = z4;
    }
    __syncthreads();

    const int lane = tid & 63, wv = tid >> 6;
    const int id = blockIdx.x;
    double* accrow = acc + (size_t)(id & ncopy_mask) * 16;

    double s0 = 0.0, ssum = 0.0;  // bin-MSE sums (vy or vx)
    int c1 = 0;

    if ((id & 1) == 0) {
        // ================= rows: vt + vy =================
        const int kid = id >> 1;  // 0..1023, 16 rows each
        double t0 = 0.0, tsum = 0.0;
        int tc1 = 0;
        unsigned* bR = bins + wv * 2000;
        unsigned* bT = bR + 1000;
        uint4* r4 = (uint4*)bR;
        uint4* t4 = (uint4*)bT;
        for (int it = 0; it < 4; it++) {
            const size_t row = (size_t)kid * 16 + (size_t)(wv * 4 + it);
            const float4* R4 = (const float4*)(R + row * 512);
            const float4* T4 = (const float4*)(T + row * 512);
#pragma unroll
            for (int k = 0; k < 2; k++) {
                const int c = lane + k * 64;  // float4 index within row
                float4 rv = R4[c];
                float4 tv = T4[c];
                float rr[4] = {rv.x, rv.y, rv.z, rv.w};
                float tt[4] = {tv.x, tv.y, tv.z, tv.w};
#pragma unroll
                for (int j = 0; j < 4; j++) {
                    float a = rr[j], b = tt[j];
                    float d = a - b, d2 = d * d;
                    bool bz = (b == 0.0f);
                    tsum += (double)d2;
                    t0 += bz ? (double)d2 : 0.0;
                    tc1 += bz ? 0 : 1;
                    scat(bR, a, (unsigned)(c * 4 + j));
                    scat(bT, b, (unsigned)(c * 4 + j));
                }
            }
            __syncthreads();
            // readback + re-clear: 250 uint4 groups per array
            for (int g = lane; g < 250; g += 64) {
                uint4 rg = r4[g], tg = t4[g];
                r4[g] = z4;
                t4[g] = z4;
                if (rg.x | rg.y | rg.z | rg.w | tg.x | tg.y | tg.z | tg.w) {
                    unsigned ru[4] = {rg.x, rg.y, rg.z, rg.w};
                    unsigned tu[4] = {tg.x, tg.y, tg.z, tg.w};
#pragma unroll
                    for (int j = 0; j < 4; j++) {
                        float rb = (float)ru[j], tb = (float)tu[j];
                        float d = rb - tb, d2 = d * d;
                        bool tz = (tb == 0.0f);
                        ssum += (double)d2;
                        s0 += tz ? (double)d2 : 0.0;
                        c1 += tz ? 0 : 1;
                    }
                }
            }
            __syncthreads();
        }
        double v0 = wred(t0), v1 = wred(tsum), v2 = wred((double)tc1);
        double v3 = wred(s0), v4 = wred(ssum), v5 = wred((double)c1);
        if (lane == 0) {
            atomicAdd(&accrow[0], v0);
            atomicAdd(&accrow[1], v1);
            atomicAdd(&accrow[2], v2);
            atomicAdd(&accrow[3], v3);
            atomicAdd(&accrow[4], v4);
            atomicAdd(&accrow[5], v5);
        }
    } else {
        // ================= columns: vx =================
        const int kid = id >> 1;    // 0..1023
        const int b = kid >> 5;     // image
        const int line = kid & 31;  // 16-column stripe
        const float* Rb = R + (size_t)b * (512 * 512) + (size_t)line * 16;
        const float* Tb = T + (size_t)b * (512 * 512) + (size_t)line * 16;

        // Load the whole stripe once. Load k: 4-lane group g=tid>>2 reads row
        // h=k*64+g; within the group, lane's quad rotates: sub=(tid+k)&3, so
        // the 4 lanes cover the row's 64B contiguously and every thread ends
        // up owning 2 register quads for each of the 4 column-phases.
        float4 ra[8], ta[8];
#pragma unroll
        for (int k = 0; k < 8; k++) {
            const int h = k * 64 + (tid >> 2);
            const int sub = (tid + k) & 3;
            const size_t off = (size_t)h * 512 + sub * 4;
            ra[k] = *(const float4*)(Rb + off);
            ta[k] = *(const float4*)(Tb + off);
        }

        uint4* r4 = (uint4*)bins;           // [4 cols][1000] for R
        uint4* t4 = (uint4*)(bins + 4000);  // [4 cols][1000] for T
#pragma unroll
        for (int p = 0; p < 4; p++) {
#pragma unroll
            for (int k = 0; k < 8; k++) {
                if (((tid + k) & 3) == p) {
                    const unsigned h = (unsigned)(k * 64 + (tid >> 2));
                    scat(bins + 0 * 1000, ra[k].x, h);
                    scat(bins + 1 * 1000, ra[k].y, h);
                    scat(bins + 2 * 1000, ra[k].z, h);
                    scat(bins + 3 * 1000, ra[k].w, h);
                    scat(bins + 4000 + 0 * 1000, ta[k].x, h);
                    scat(bins + 4000 + 1 * 1000, ta[k].y, h);
                    scat(bins + 4000 + 2 * 1000, ta[k].z, h);
                    scat(bins + 4000 + 3 * 1000, ta[k].w, h);
                }
            }
            __syncthreads();
            // readback + re-clear: 1000 uint4 groups cover all 4 columns
            for (int g = tid; g < 1000; g += 256) {
                uint4 rg = r4[g], tg = t4[g];
                r4[g] = z4;
                t4[g] = z4;
                if (rg.x | rg.y | rg.z | rg.w | tg.x | tg.y | tg.z | tg.w) {
                    unsigned ru[4] = {rg.x, rg.y, rg.z, rg.w};
                    unsigned tu[4] = {tg.x, tg.y, tg.z, tg.w};
#pragma unroll
                    for (int j = 0; j < 4; j++) {
                        float rb = (float)ru[j], tb = (float)tu[j];
                        float d = rb - tb, d2 = d * d;
                        bool tz = (tb == 0.0f);
                        ssum += (double)d2;
                        s0 += tz ? (double)d2 : 0.0;
                        c1 += tz ? 0 : 1;
                    }
                }
            }
            __syncthreads();
        }
        double v3 = wred(s0), v4 = wred(ssum), v5 = wred((double)c1);
        if (lane == 0) {
            atomicAdd(&accrow[6], v3);
            atomicAdd(&accrow[7], v4);
            atomicAdd(&accrow[8], v5);
        }
    }
}

__global__ void kfin(const double* __restrict__ acc, float* __restrict__ out,
                     int ncopy) {
    const int lane = threadIdx.x;  // 64 threads
    double v[9];
#pragma unroll
    for (int k = 0; k < 9; k++) v[k] = 0.0;
    if (lane < ncopy) {
#pragma unroll
        for (int k = 0; k < 9; k++) v[k] = acc[(size_t)lane * 16 + k];
    }
#pragma unroll
    for (int k = 0; k < 9; k++) {
#pragma unroll
        for (int o = 16; o > 0; o >>= 1) v[k] += __shfl_down(v[k], o, 64);
    }
    if (lane == 0) {
        const double NT = 8388608.0;   // 32*512*512
        const double NB = 16384000.0;  // 32*512*1000
        double vt_c1 = v[2], vy_c1 = v[5], vx_c1 = v[8];
        double vt_c0 = NT - vt_c1, vy_c0 = NB - vy_c1, vx_c0 = NB - vx_c1;
        double vt_s1 = v[1] - v[0];
        double vy_s1 = v[4] - v[3];
        double vx_s1 = v[7] - v[6];
        double vt = (vt_c0 > 0.0 ? v[0] / vt_c0 : 0.0) +
                    (vt_c1 > 0.0 ? vt_s1 / vt_c1 : 0.0);
        double vy = (vy_c0 > 0.0 ? v[3] / vy_c0 : 0.0) +
                    (vy_c1 > 0.0 ? vy_s1 / vy_c1 : 0.0);
        double vx = (vx_c0 > 0.0 ? v[6] / vx_c0 : 0.0) +
                    (vx_c1 > 0.0 ? vx_s1 / vx_c1 : 0.0);
        out[0] = (float)(vt + vx + vy);
    }
}

extern "C" void kernel_launch(void* const* d_in, const int* in_sizes, int n_in,
                              void* d_out, int out_size, void* d_ws, size_t ws_size,
                              hipStream_t stream) {
    const float* R = (const float*)d_in[0];  // reconstructed_image
    const float* T = (const float*)d_in[1];  // target_image
    double* acc = (double*)d_ws;
    float* out = (float*)d_out;

    int ncopy = 16;
    while (ncopy > 1 && (size_t)ncopy * 16 * sizeof(double) > ws_size) ncopy >>= 1;

    hipLaunchKernelGGL(kinit, dim3(1), dim3(256), 0, stream, acc, ncopy * 16);
    hipLaunchKernelGGL(kmain, dim3(2048), dim3(256), 0, stream, R, T, acc, ncopy - 1);
    hipLaunchKernelGGL(kfin, dim3(1), dim3(64), 0, stream, acc, out, ncopy);
}